// Round 3
// baseline (112.247 us; speedup 1.0000x reference)
//
#include <hip/hip_runtime.h>
#include <math.h>

#define NB 16
#define NA 3
#define GS 4096                 // 64*64 spatial
#define NPOS (NB * NA * GS)     // 196608
#define POSB 256                // positions per block -> 1KB read segments per plane

__device__ __forceinline__ float sigmoidf_(float v) {
    return 1.0f / (1.0f + __expf(-v));
}

// Block = one (b,a) pair x 256 consecutive spatial positions.
// Read:  80 cls planes as 1-KB segments; each wave-instr (dwordx4 x 64 lanes)
//        covers exactly one full plane segment. 10 planes per wave.
// LDS:   [80][256] floats, 81920 B (2 blocks/CU = exactly 160 KiB).
//        Quad-XOR swizzle q ^= (ch>>2)&7: write side conflict-free b128,
//        read side ~2-3-way (c4 spreads banks).
// Write: 256x80 cls tile = contiguous 80KB region, dwordx4; box/conf by waves 0-3.
__global__ __launch_bounds__(512, 4) void yolo_kernel(const float* __restrict__ x,
                                                      const float* __restrict__ anchors,
                                                      float* __restrict__ out) {
    __shared__ float lds[80 * POSB];        // 81920 B
    const int tid   = threadIdx.x;
    const int w     = tid >> 6;             // wave 0..7
    const int l     = tid & 63;             // lane = quad index within plane segment
    const int ba    = blockIdx.x >> 4;      // (b,a) pair 0..47
    const int chunk = blockIdx.x & 15;      // 256-pos chunk 0..15
    const int s0    = chunk << 8;
    const float* __restrict__ xb = x + (size_t)ba * 85 * GS + s0;

    // ---- cls loads: wave w owns planes ch = w + 8k; 1 instr = 1 full 1KB segment ----
    const float* __restrict__ xc = xb + (size_t)(5 + w) * GS + l * 4;
    float4 v[10];
    #pragma unroll
    for (int k = 0; k < 10; ++k)
        v[k] = *reinterpret_cast<const float4*>(xc + (size_t)(8 * k) * GS);

    // ---- box loads: waves 0-3, one position each (256-B segments x 5 planes) ----
    float tx = 0.f, ty = 0.f, tw = 0.f, th = 0.f, tc = 0.f;
    const bool box_lane = (tid < POSB);
    if (box_lane) {
        tx = xb[0 * GS + tid];
        ty = xb[1 * GS + tid];
        tw = xb[2 * GS + tid];
        th = xb[3 * GS + tid];
        tc = xb[4 * GS + tid];
    }

    // ---- sigmoid + swizzled LDS store: conflict-free b128 (full-row permutation) ----
    #pragma unroll
    for (int k = 0; k < 10; ++k) {
        const int ch = w + 8 * k;
        const int qs = l ^ ((ch >> 2) & 7);
        float4 sv;
        sv.x = sigmoidf_(v[k].x);
        sv.y = sigmoidf_(v[k].y);
        sv.z = sigmoidf_(v[k].z);
        sv.w = sigmoidf_(v[k].w);
        *reinterpret_cast<float4*>(&lds[ch * POSB + qs * 4]) = sv;
    }

    // ---- box compute + store (pre-barrier, independent of LDS) ----
    if (box_lane) {
        const int p = s0 + tid;             // spatial index within (b,a)
        const int t = ba * GS + p;          // global position index
        const int a = ba % NA;
        float4 box;
        box.x = (sigmoidf_(tx) + (float)(p >> 6)) * (1.0f / 64.0f);  // grid_x = row
        box.y = (sigmoidf_(ty) + (float)(p & 63)) * (1.0f / 64.0f);  // grid_y = col
        box.z = __expf(tw) * anchors[a * 2 + 0];
        box.w = __expf(th) * anchors[a * 2 + 1];
        reinterpret_cast<float4*>(out)[t] = box;
        out[(size_t)NPOS * 4 + t] = sigmoidf_(tc);
    }

    __syncthreads();

    // ---- cls writes: contiguous 80KB tile, 10 x dwordx4 per thread ----
    float4* __restrict__ out4 =
        reinterpret_cast<float4*>(out + (size_t)NPOS * 5) + (size_t)(ba * GS + s0) * 20;
    #pragma unroll
    for (int k = 0; k < 10; ++k) {
        const int o4 = tid + (k << 9);      // 0..5119
        const int p  = o4 / 20;             // local position 0..255 (magic-mul)
        const int c4 = o4 - p * 20;         // channel quad 0..19
        const int qs = (p >> 2) ^ (c4 & 7); // undo swizzle: ch>>2 == c4 for all 4 ch
        const int pb = p & 3;
        float4 w4;
        w4.x = lds[(4 * c4 + 0) * POSB + qs * 4 + pb];
        w4.y = lds[(4 * c4 + 1) * POSB + qs * 4 + pb];
        w4.z = lds[(4 * c4 + 2) * POSB + qs * 4 + pb];
        w4.w = lds[(4 * c4 + 3) * POSB + qs * 4 + pb];
        out4[o4] = w4;
    }
}

extern "C" void kernel_launch(void* const* d_in, const int* in_sizes, int n_in,
                              void* d_out, int out_size, void* d_ws, size_t ws_size,
                              hipStream_t stream) {
    const float* x       = (const float*)d_in[0];
    const float* anchors = (const float*)d_in[1];
    float* out           = (float*)d_out;
    const int blocks = NB * NA * 16;        // 768 blocks: one per (b,a, 256-pos chunk)
    yolo_kernel<<<blocks, 512, 0, stream>>>(x, anchors, out);
}